// Round 10
// baseline (250.060 us; speedup 1.0000x reference)
//
#include <hip/hip_runtime.h>
#include <cstdint>
#include <cstddef>

#define N_NODES 50000
#define BN_EPS 1e-5f
#define NPB 256                         // nodes per bucket
#define NB ((N_NODES + NPB - 1) / NPB)  // 196 buckets
#define EPB 2048                        // edges per build block
#define BN_BLOCKS 256

typedef unsigned int uint32;
typedef unsigned short ushort;

typedef short bf16x8 __attribute__((ext_vector_type(8)));
typedef float f32x4 __attribute__((ext_vector_type(4)));

// ---------------- helpers ----------------

__device__ inline ushort bf16rn(float f) {
  unsigned int u = __float_as_uint(f);
  u += 0x7fffu + ((u >> 16) & 1u);
  return (ushort)(u >> 16);
}
__device__ inline float unbf(uint32 u) { return __uint_as_float(u << 16); }
__device__ inline float lo16(uint32 u) { return __uint_as_float(u << 16); }
__device__ inline float hi16(uint32 u) { return __uint_as_float(u & 0xffff0000u); }
__device__ inline uint32 pack2(float a, float b) {
  return (uint32)bf16rn(a) | ((uint32)bf16rn(b) << 16);
}

// ---------------- weight convert (all 3): Wt[c][k] = bf16(W[k][c]) ----------------

__global__ __launch_bounds__(256) void k_cvtW_all(const float* __restrict__ W1,
    const float* __restrict__ W2, const float* __restrict__ W3,
    ushort* __restrict__ Wt1, ushort* __restrict__ Wt2, ushort* __restrict__ Wt3) {
  int gid = blockIdx.x * 256 + threadIdx.x;
  if (gid < 16384) {
    int c = gid >> 7, k = gid & 127;
    Wt1[c * 128 + k] = bf16rn(W1[(size_t)k * 128 + c]);
  } else if (gid < 32768) {
    int g = gid - 16384, c = g >> 7, k = g & 127;
    Wt2[c * 128 + k] = bf16rn(W2[(size_t)k * 128 + c]);
  } else if (gid < 37888) {
    int g = gid - 32768, c = g >> 7, k = g & 127;
    Wt3[c * 128 + k] = bf16rn(W3[(size_t)k * 40 + c]);
  }
}

// ---------------- CSR build: binned two-phase ----------------

// per-bucket histogram; saves per-block hist; last block runs serial prefix
__global__ __launch_bounds__(256) void k_ehist(const int* __restrict__ dst, int E,
    int* __restrict__ histB, int* __restrict__ hists, int* __restrict__ done,
    int* __restrict__ rbase, int* __restrict__ cbase, int* __restrict__ start) {
  __shared__ int h[NB];
  for (int i = threadIdx.x; i < NB; i += 256) h[i] = 0;
  __syncthreads();
  int base = blockIdx.x * EPB;
  for (int i = threadIdx.x; i < EPB; i += 256) {
    int e = base + i;
    if (e < E) atomicAdd(&h[dst[e] >> 8], 1);
  }
  __syncthreads();
  for (int i = threadIdx.x; i < NB; i += 256) {
    int v = h[i];
    hists[blockIdx.x * NB + i] = v;
    if (v) atomicAdd(&histB[i], v);
  }
  if (threadIdx.x == 0) {
    __threadfence();
    int old = atomicAdd(done, 1);
    if (old == gridDim.x - 1) {
      __threadfence();
      int r = 0, c = 0;
      for (int b = 0; b < NB; ++b) {
        int npb = (b == NB - 1) ? (N_NODES - b * NPB) : NPB;
        rbase[b] = r; cbase[b] = c;
        r += histB[b]; c += histB[b] + npb;
      }
      rbase[NB] = r;
      start[N_NODES] = c;   // == E + N_NODES
    }
  }
}

__global__ __launch_bounds__(256) void k_binA(const int* __restrict__ src,
    const int* __restrict__ dst, const float* __restrict__ ew, int E,
    const int* __restrict__ rbase, const int* __restrict__ hists,
    int* __restrict__ gcur, uint2* __restrict__ bins) {
  __shared__ int gb[NB], cur[NB];
  for (int i = threadIdx.x; i < NB; i += 256) {
    int hv = hists[blockIdx.x * NB + i];
    cur[i] = 0;
    gb[i] = hv ? (rbase[i] + atomicAdd(&gcur[i], hv)) : 0;
  }
  __syncthreads();
  int base = blockIdx.x * EPB;
  for (int i = threadIdx.x; i < EPB; i += 256) {
    int e = base + i;
    if (e < E) {
      int d = dst[e];
      int g = d >> 8;
      int p = gb[g] + atomicAdd(&cur[g], 1);
      bins[p] = make_uint2((uint32)src[e] | ((uint32)(d & 255) << 16),
                           __float_as_uint(ew[e]));
    }
  }
}

__global__ __launch_bounds__(256) void k_binB(const uint2* __restrict__ bins,
    const int* __restrict__ rbase, const int* __restrict__ cbase,
    int* __restrict__ start, float* __restrict__ dinv, uint32* __restrict__ csr) {
  __shared__ int h[256], cur[256], ofs[256], sc[256];
  __shared__ float deg[256];
  int tid = threadIdx.x;
  int b = blockIdx.x;
  int node0 = b << 8;
  int npb = min(NPB, N_NODES - node0);
  h[tid] = 0; deg[tid] = 1.0f;
  __syncthreads();
  int r0 = rbase[b], r1 = rbase[b + 1];
  for (int i = r0 + tid; i < r1; i += 256) {
    uint2 rec = bins[i];
    int dl = (rec.x >> 16) & 255;
    atomicAdd(&h[dl], 1);
    atomicAdd(&deg[dl], __uint_as_float(rec.y));
  }
  __syncthreads();
  int v = (tid < npb) ? 1 + h[tid] : 0;
  sc[tid] = v;
  __syncthreads();
  for (int off = 1; off < 256; off <<= 1) {
    int a = (tid >= off) ? sc[tid - off] : 0;
    __syncthreads();
    sc[tid] += a;
    __syncthreads();
  }
  int cb = cbase[b];
  if (tid < npb) {
    int segBase = cb + sc[tid] - v;
    int node = node0 + tid;
    start[node] = segBase;
    csr[segBase] = (0x3F80u << 16) | (uint32)node;   // self: w=1.0
    dinv[node] = rsqrtf(deg[tid]);
    ofs[tid] = segBase + 1;
    cur[tid] = 0;
  }
  __syncthreads();
  for (int i = r0 + tid; i < r1; i += 256) {
    uint2 rec = bins[i];
    int dl = (rec.x >> 16) & 255;
    int p = ofs[dl] + atomicAdd(&cur[dl], 1);
    csr[p] = ((uint32)bf16rn(__uint_as_float(rec.y)) << 16) | (rec.x & 0xffff);
  }
}

__global__ __launch_bounds__(256) void k_wnorm(uint32* __restrict__ csr,
    const int* __restrict__ start, const float* __restrict__ dinv) {
  int lane = threadIdx.x & 15;
  int node = blockIdx.x * 16 + (threadIdx.x >> 4);
  if (node >= N_NODES) return;
  float di = dinv[node];
  int e0 = start[node], e1 = start[node + 1];
  for (int e = e0 + lane; e < e1; e += 16) {
    uint32 c = csr[e];
    int s = c & 0xffff;
    float w = unbf(c >> 16) * dinv[s] * di;
    csr[e] = ((uint32)bf16rn(w) << 16) | (uint32)s;
  }
}

// ---------------- MFMA GEMM (+ fused BN+ReLU on input via precomputed ssb) ----------------

template <int BNT, typename XT>
__global__ __launch_bounds__(256) void k_mfma(const XT* __restrict__ X,
    const ushort* __restrict__ Wt, const float* __restrict__ ssb,
    ushort* __restrict__ out16, int Fout) {
  __shared__ ushort Xs[64][136];
  __shared__ ushort Bs[BNT * 16][136];
  int tid = threadIdx.x;
  int r0 = blockIdx.x * 64;

  // stage Bs[col][k]
  for (int idx = tid; idx < BNT * 16 * 16; idx += 256) {
    int col = idx >> 4;
    int kk = (idx & 15) * 8;
    uint4 v = make_uint4(0, 0, 0, 0);
    if (col < Fout)
      v = *reinterpret_cast<const uint4*>(&Wt[(size_t)col * 128 + kk]);
    *reinterpret_cast<uint4*>(&Bs[col][kk]) = v;
  }

  // stage Xs[row][k]
  if (sizeof(XT) == 4) {
    const float* Xf = reinterpret_cast<const float*>(X);
    for (int idx = tid; idx < 2048; idx += 256) {
      int row = idx >> 5;
      int kk = (idx & 31) * 4;
      int gr = r0 + row;
      float4 v = make_float4(0.f, 0.f, 0.f, 0.f);
      if (gr < N_NODES)
        v = *reinterpret_cast<const float4*>(&Xf[(size_t)gr * 128 + kk]);
      ushort4 o;
      o.x = bf16rn(v.x); o.y = bf16rn(v.y); o.z = bf16rn(v.z); o.w = bf16rn(v.w);
      *reinterpret_cast<ushort4*>(&Xs[row][kk]) = o;
    }
  } else {
    const ushort* X16 = reinterpret_cast<const ushort*>(X);
    for (int idx = tid; idx < 1024; idx += 256) {
      int row = idx >> 4;
      int kk = (idx & 15) * 8;
      int gr = r0 + row;
      uint4 v = make_uint4(0, 0, 0, 0);
      if (gr < N_NODES)
        v = *reinterpret_cast<const uint4*>(&X16[(size_t)gr * 128 + kk]);
      if (ssb) {
        float f[8] = { lo16(v.x), hi16(v.x), lo16(v.y), hi16(v.y),
                       lo16(v.z), hi16(v.z), lo16(v.w), hi16(v.w) };
        float4 sc0 = *reinterpret_cast<const float4*>(&ssb[kk]);
        float4 sc1 = *reinterpret_cast<const float4*>(&ssb[kk + 4]);
        float4 sh0 = *reinterpret_cast<const float4*>(&ssb[128 + kk]);
        float4 sh1 = *reinterpret_cast<const float4*>(&ssb[128 + kk + 4]);
        f[0] = fmaxf(0.f, f[0] * sc0.x + sh0.x);
        f[1] = fmaxf(0.f, f[1] * sc0.y + sh0.y);
        f[2] = fmaxf(0.f, f[2] * sc0.z + sh0.z);
        f[3] = fmaxf(0.f, f[3] * sc0.w + sh0.w);
        f[4] = fmaxf(0.f, f[4] * sc1.x + sh1.x);
        f[5] = fmaxf(0.f, f[5] * sc1.y + sh1.y);
        f[6] = fmaxf(0.f, f[6] * sc1.z + sh1.z);
        f[7] = fmaxf(0.f, f[7] * sc1.w + sh1.w);
        v.x = pack2(f[0], f[1]); v.y = pack2(f[2], f[3]);
        v.z = pack2(f[4], f[5]); v.w = pack2(f[6], f[7]);
      }
      *reinterpret_cast<uint4*>(&Xs[row][kk]) = v;
    }
  }
  __syncthreads();

  int lane = tid & 63, wav = tid >> 6;
  int lrow = lane & 15, lk = (lane >> 4) * 8;
  f32x4 acc[BNT];
  #pragma unroll
  for (int ct = 0; ct < BNT; ++ct) acc[ct] = (f32x4){0.f, 0.f, 0.f, 0.f};

  #pragma unroll
  for (int kc = 0; kc < 4; ++kc) {
    int k0 = kc * 32 + lk;
    bf16x8 a = *reinterpret_cast<const bf16x8*>(&Xs[wav * 16 + lrow][k0]);
    #pragma unroll
    for (int ct = 0; ct < BNT; ++ct) {
      bf16x8 b = *reinterpret_cast<const bf16x8*>(&Bs[ct * 16 + lrow][k0]);
      acc[ct] = __builtin_amdgcn_mfma_f32_16x16x32_bf16(a, b, acc[ct], 0, 0, 0);
    }
  }

  int orow = wav * 16 + (lane >> 4) * 4;
  #pragma unroll
  for (int ct = 0; ct < BNT; ++ct) {
    int gc = ct * 16 + lrow;
    if (gc >= Fout) continue;
    #pragma unroll
    for (int i = 0; i < 4; ++i) {
      int gr = r0 + orow + i;
      if (gr < N_NODES) out16[(size_t)gr * Fout + gc] = bf16rn(acc[ct][i]);
    }
  }
}

// ---------------- aggregation: 1 wave/node, 8 rows in flight ----------------

__global__ __launch_bounds__(256) void k_agg128c(const ushort* __restrict__ xw,
    const float* __restrict__ bias, const int* __restrict__ start,
    const uint32* __restrict__ csr, ushort* __restrict__ out16) {
  int lane = threadIdx.x & 63;
  int node = blockIdx.x * 4 + (threadIdx.x >> 6);
  if (node >= N_NODES) return;
  int sub = lane >> 4;
  int fl  = lane & 15;
  const uint4* rows = (const uint4*)xw;
  float acc[8] = {};
  int e0 = start[node], e1 = start[node + 1];
  int e = e0 + sub;
  for (; e + 4 < e1; e += 8) {
    uint32 c0 = csr[e], c1 = csr[e + 4];
    uint4 v0 = rows[(size_t)(c0 & 0xffff) * 16 + fl];
    uint4 v1 = rows[(size_t)(c1 & 0xffff) * 16 + fl];
    float w0 = unbf(c0 >> 16), w1 = unbf(c1 >> 16);
    acc[0] += w0 * lo16(v0.x) + w1 * lo16(v1.x);
    acc[1] += w0 * hi16(v0.x) + w1 * hi16(v1.x);
    acc[2] += w0 * lo16(v0.y) + w1 * lo16(v1.y);
    acc[3] += w0 * hi16(v0.y) + w1 * hi16(v1.y);
    acc[4] += w0 * lo16(v0.z) + w1 * lo16(v1.z);
    acc[5] += w0 * hi16(v0.z) + w1 * hi16(v1.z);
    acc[6] += w0 * lo16(v0.w) + w1 * lo16(v1.w);
    acc[7] += w0 * hi16(v0.w) + w1 * hi16(v1.w);
  }
  if (e < e1) {
    uint32 c = csr[e];
    float w = unbf(c >> 16);
    uint4 v = rows[(size_t)(c & 0xffff) * 16 + fl];
    acc[0] += w * lo16(v.x); acc[1] += w * hi16(v.x);
    acc[2] += w * lo16(v.y); acc[3] += w * hi16(v.y);
    acc[4] += w * lo16(v.z); acc[5] += w * hi16(v.z);
    acc[6] += w * lo16(v.w); acc[7] += w * hi16(v.w);
  }
  #pragma unroll
  for (int k = 0; k < 8; ++k) acc[k] += __shfl_xor(acc[k], 16);
  #pragma unroll
  for (int k = 0; k < 8; ++k) acc[k] += __shfl_xor(acc[k], 32);
  if (sub == 0) {
    float4 b0 = ((const float4*)bias)[fl * 2];
    float4 b1 = ((const float4*)bias)[fl * 2 + 1];
    acc[0] += b0.x; acc[1] += b0.y; acc[2] += b0.z; acc[3] += b0.w;
    acc[4] += b1.x; acc[5] += b1.y; acc[6] += b1.z; acc[7] += b1.w;
    uint4 o;
    o.x = pack2(acc[0], acc[1]);
    o.y = pack2(acc[2], acc[3]);
    o.z = pack2(acc[4], acc[5]);
    o.w = pack2(acc[6], acc[7]);
    ((uint4*)out16)[(size_t)node * 16 + fl] = o;
  }
}

// ---------------- agg (40 cols) + fused log_softmax ----------------

__global__ __launch_bounds__(256) void k_agg40lsm(const ushort* __restrict__ xw,
    const float* __restrict__ bias, const int* __restrict__ start,
    const uint32* __restrict__ csr, float* __restrict__ out) {
  int lane = threadIdx.x & 63;
  int node = blockIdx.x * 4 + (threadIdx.x >> 6);
  if (node >= N_NODES) return;
  int sub = lane >> 4;
  int fl  = lane & 15;
  bool active = fl < 10;
  int flc = active ? fl : 0;
  const uint2* rows = (const uint2*)xw;
  float acc[4] = {};
  int e0 = start[node], e1 = start[node + 1];
  for (int e = e0 + sub; e < e1; e += 4) {
    uint32 c = csr[e];
    float w = unbf(c >> 16);
    int s = c & 0xffff;
    uint2 v = rows[(size_t)s * 10 + flc];
    if (active) {
      acc[0] += w * lo16(v.x); acc[1] += w * hi16(v.x);
      acc[2] += w * lo16(v.y); acc[3] += w * hi16(v.y);
    }
  }
  #pragma unroll
  for (int k = 0; k < 4; ++k) acc[k] += __shfl_xor(acc[k], 16);
  #pragma unroll
  for (int k = 0; k < 4; ++k) acc[k] += __shfl_xor(acc[k], 32);
  if (sub == 0) {
    float m = -1e30f, es = 0.f;
    if (active) {
      float4 b = ((const float4*)bias)[fl];
      acc[0] += b.x; acc[1] += b.y; acc[2] += b.z; acc[3] += b.w;
      m = fmaxf(fmaxf(acc[0], acc[1]), fmaxf(acc[2], acc[3]));
    }
    #pragma unroll
    for (int off = 8; off >= 1; off >>= 1) m = fmaxf(m, __shfl_xor(m, off, 16));
    if (active)
      es = expf(acc[0] - m) + expf(acc[1] - m) + expf(acc[2] - m) + expf(acc[3] - m);
    #pragma unroll
    for (int off = 8; off >= 1; off >>= 1) es += __shfl_xor(es, off, 16);
    if (active) {
      float lse = m + logf(es);
      float4 o = make_float4(acc[0] - lse, acc[1] - lse, acc[2] - lse, acc[3] - lse);
      *reinterpret_cast<float4*>(&out[(size_t)node * 40 + fl * 4]) = o;
    }
  }
}

// ---------------- batch norm stats (no atomics) + fused final reduce ----------------

__global__ __launch_bounds__(256) void k_bnstats1(const ushort* __restrict__ x,
    float* __restrict__ partials, int* __restrict__ done,
    const float* __restrict__ gamma, const float* __restrict__ beta,
    float* __restrict__ ssb) {
  int tid = threadIdx.x;
  int fl = tid & 15;     // feature group (8 features)
  int rg = tid >> 4;     // 16 row-groups
  float s[8] = {}, q[8] = {};
  const uint4* xv = (const uint4*)x;
  for (int row = blockIdx.x * 16 + rg; row < N_NODES; row += BN_BLOCKS * 16) {
    uint4 v = xv[(size_t)row * 16 + fl];
    float f0 = lo16(v.x), f1 = hi16(v.x), f2 = lo16(v.y), f3 = hi16(v.y);
    float f4 = lo16(v.z), f5 = hi16(v.z), f6 = lo16(v.w), f7 = hi16(v.w);
    s[0] += f0; q[0] += f0 * f0; s[1] += f1; q[1] += f1 * f1;
    s[2] += f2; q[2] += f2 * f2; s[3] += f3; q[3] += f3 * f3;
    s[4] += f4; q[4] += f4 * f4; s[5] += f5; q[5] += f5 * f5;
    s[6] += f6; q[6] += f6 * f6; s[7] += f7; q[7] += f7 * f7;
  }
  __shared__ float ls[256][8];
  __shared__ float lq[256][8];
  #pragma unroll
  for (int j = 0; j < 8; ++j) { ls[tid][j] = s[j]; lq[tid][j] = q[j]; }
  __syncthreads();
  for (int step = 8; step >= 1; step >>= 1) {
    if (rg < step) {
      #pragma unroll
      for (int j = 0; j < 8; ++j) {
        ls[rg * 16 + fl][j] += ls[(rg + step) * 16 + fl][j];
        lq[rg * 16 + fl][j] += lq[(rg + step) * 16 + fl][j];
      }
    }
    __syncthreads();
  }
  if (rg == 0) {
    #pragma unroll
    for (int j = 0; j < 8; ++j) {
      partials[(size_t)blockIdx.x * 256 + fl * 8 + j] = ls[fl][j];
      partials[(size_t)blockIdx.x * 256 + 128 + fl * 8 + j] = lq[fl][j];
    }
  }
  __shared__ int isLast;
  __syncthreads();
  if (tid == 0) {
    __threadfence();
    isLast = (atomicAdd(done, 1) == BN_BLOCKS - 1) ? 1 : 0;
  }
  __syncthreads();
  if (isLast) {
    __threadfence();
    float acc = 0.f;
    for (int b = 0; b < BN_BLOCKS; ++b) acc += partials[(size_t)b * 256 + tid];
    __shared__ float st[256];
    st[tid] = acc;
    __syncthreads();
    if (tid < 128) {
      float inv_n = 1.0f / (float)N_NODES;
      float mu = st[tid] * inv_n;
      float var = st[128 + tid] * inv_n - mu * mu;
      if (var < 0.f) var = 0.f;
      float sc = gamma[tid] * rsqrtf(var + BN_EPS);
      ssb[tid] = sc;
      ssb[128 + tid] = beta[tid] - mu * sc;
    }
  }
}

// ---------------- launch ----------------

extern "C" void kernel_launch(void* const* d_in, const int* in_sizes, int n_in,
                              void* d_out, int out_size, void* d_ws, size_t ws_size,
                              hipStream_t stream) {
  const float* x   = (const float*)d_in[0];
  const int*   ei  = (const int*)d_in[1];
  const float* ew  = (const float*)d_in[2];
  const float* W1  = (const float*)d_in[3];
  const float* b1  = (const float*)d_in[4];
  const float* g1  = (const float*)d_in[5];
  const float* be1 = (const float*)d_in[6];
  const float* W2  = (const float*)d_in[7];
  const float* b2  = (const float*)d_in[8];
  const float* g2  = (const float*)d_in[9];
  const float* be2 = (const float*)d_in[10];
  const float* W3  = (const float*)d_in[11];
  const float* b3  = (const float*)d_in[12];
  float* out = (float*)d_out;
  int E = in_sizes[2];
  const int* src = ei;
  const int* dst = ei + E;
  int nblkA = (E + EPB - 1) / EPB;

  char* p = (char*)d_ws;
  auto alloc = [&](size_t bytes) {
    char* r = p; p += (bytes + 255) & ~(size_t)255; return r;
  };
  // zero-initialized region (single memset): histB, gcur, done counters
  int*    histB  = (int*)   alloc((size_t)(NB + 1) * 4);
  int*    gcur   = (int*)   alloc((size_t)NB * 4);
  int*    doneE  = (int*)   alloc(4);
  int*    doneB1 = (int*)   alloc(4);
  int*    doneB2 = (int*)   alloc(4);
  size_t zspan = (size_t)((char*)doneB2 + 4 - (char*)histB);
  int*    rbase  = (int*)   alloc((size_t)(NB + 1) * 4);
  int*    cbase  = (int*)   alloc((size_t)NB * 4);
  int*    hists  = (int*)   alloc((size_t)nblkA * NB * 4);
  int*    startA = (int*)   alloc((size_t)(N_NODES + 1) * 4);
  float*  dinv   = (float*) alloc((size_t)N_NODES * 4);
  uint2*  bins   = (uint2*) alloc((size_t)E * 8);
  uint32* csr    = (uint32*)alloc((size_t)(E + N_NODES) * 4);
  float*  parts  = (float*) alloc((size_t)BN_BLOCKS * 256 * 4);
  float*  ssb1   = (float*) alloc(256 * 4);
  float*  ssb2   = (float*) alloc(256 * 4);
  ushort* Wt1    = (ushort*)alloc((size_t)128 * 128 * 2);
  ushort* Wt2    = (ushort*)alloc((size_t)128 * 128 * 2);
  ushort* Wt3    = (ushort*)alloc((size_t)40 * 128 * 2);
  ushort* xw16   = (ushort*)alloc((size_t)N_NODES * 128 * 2);
  ushort* buf16  = (ushort*)alloc((size_t)N_NODES * 128 * 2);

  hipMemsetAsync(histB, 0, zspan, stream);
  k_cvtW_all<<<149, 256, 0, stream>>>(W1, W2, W3, Wt1, Wt2, Wt3);
  k_ehist<<<nblkA, 256, 0, stream>>>(dst, E, histB, hists, doneE, rbase, cbase, startA);
  k_binA<<<nblkA, 256, 0, stream>>>(src, dst, ew, E, rbase, hists, gcur, bins);
  k_binB<<<NB, 256, 0, stream>>>(bins, rbase, cbase, startA, dinv, csr);
  k_wnorm<<<(N_NODES + 15) / 16, 256, 0, stream>>>(csr, startA, dinv);

  int gemmGrid = (N_NODES + 63) / 64;   // 782
  int aggGrid = (N_NODES + 3) / 4;

  // layer 1
  k_mfma<8, float><<<gemmGrid, 256, 0, stream>>>(x, Wt1, nullptr, xw16, 128);
  k_agg128c<<<aggGrid, 256, 0, stream>>>(xw16, b1, startA, csr, buf16);
  k_bnstats1<<<BN_BLOCKS, 256, 0, stream>>>(buf16, parts, doneB1, g1, be1, ssb1);

  // layer 2 (BN1+ReLU fused into GEMM staging)
  k_mfma<8, ushort><<<gemmGrid, 256, 0, stream>>>(buf16, Wt2, ssb1, xw16, 128);
  k_agg128c<<<aggGrid, 256, 0, stream>>>(xw16, b2, startA, csr, buf16);
  k_bnstats1<<<BN_BLOCKS, 256, 0, stream>>>(buf16, parts, doneB2, g2, be2, ssb2);

  // layer 3 (BN2+ReLU fused into GEMM staging; agg + log_softmax fused)
  k_mfma<3, ushort><<<gemmGrid, 256, 0, stream>>>(buf16, Wt3, ssb2, xw16, 40);
  k_agg40lsm<<<aggGrid, 256, 0, stream>>>(xw16, b3, startA, csr, out);
}

// Round 11
// 235.082 us; speedup vs baseline: 1.0637x; 1.0637x over previous
//
#include <hip/hip_runtime.h>
#include <cstdint>
#include <cstddef>

#define N_NODES 50000
#define BN_EPS 1e-5f
#define NPB 256                         // nodes per bucket
#define NB ((N_NODES + NPB - 1) / NPB)  // 196 buckets
#define EPB 2048                        // edges per build block
#define BN_BLOCKS 128

typedef unsigned int uint32;
typedef unsigned short ushort;

typedef short bf16x8 __attribute__((ext_vector_type(8)));
typedef float f32x4 __attribute__((ext_vector_type(4)));

// ---------------- helpers ----------------

__device__ inline ushort bf16rn(float f) {
  unsigned int u = __float_as_uint(f);
  u += 0x7fffu + ((u >> 16) & 1u);
  return (ushort)(u >> 16);
}
__device__ inline float unbf(uint32 u) { return __uint_as_float(u << 16); }
__device__ inline float lo16(uint32 u) { return __uint_as_float(u << 16); }
__device__ inline float hi16(uint32 u) { return __uint_as_float(u & 0xffff0000u); }
__device__ inline uint32 pack2(float a, float b) {
  return (uint32)bf16rn(a) | ((uint32)bf16rn(b) << 16);
}

// ---------------- weight convert (all 3): Wt[c][k] = bf16(W[k][c]) ----------------

__global__ __launch_bounds__(256) void k_cvtW_all(const float* __restrict__ W1,
    const float* __restrict__ W2, const float* __restrict__ W3,
    ushort* __restrict__ Wt1, ushort* __restrict__ Wt2, ushort* __restrict__ Wt3) {
  int gid = blockIdx.x * 256 + threadIdx.x;
  if (gid < 16384) {
    int c = gid >> 7, k = gid & 127;
    Wt1[c * 128 + k] = bf16rn(W1[(size_t)k * 128 + c]);
  } else if (gid < 32768) {
    int g = gid - 16384, c = g >> 7, k = g & 127;
    Wt2[c * 128 + k] = bf16rn(W2[(size_t)k * 128 + c]);
  } else if (gid < 37888) {
    int g = gid - 32768, c = g >> 7, k = g & 127;
    Wt3[c * 128 + k] = bf16rn(W3[(size_t)k * 40 + c]);
  }
}

// ---------------- CSR build: binned two-phase ----------------

__global__ __launch_bounds__(256) void k_ehist(const int* __restrict__ dst, int E,
    int* __restrict__ histB, int* __restrict__ hists) {
  __shared__ int h[NB];
  for (int i = threadIdx.x; i < NB; i += 256) h[i] = 0;
  __syncthreads();
  int base = blockIdx.x * EPB;
  for (int i = threadIdx.x; i < EPB; i += 256) {
    int e = base + i;
    if (e < E) atomicAdd(&h[dst[e] >> 8], 1);
  }
  __syncthreads();
  for (int i = threadIdx.x; i < NB; i += 256) {
    int v = h[i];
    hists[blockIdx.x * NB + i] = v;
    if (v) atomicAdd(&histB[i], v);
  }
}

__global__ void k_prefix(const int* __restrict__ histB, int E,
                         int* __restrict__ rbase, int* __restrict__ cbase,
                         int* __restrict__ start) {
  if (threadIdx.x == 0 && blockIdx.x == 0) {
    int r = 0, c = 0;
    for (int b = 0; b < NB; ++b) {
      int npb = (b == NB - 1) ? (N_NODES - b * NPB) : NPB;
      rbase[b] = r; cbase[b] = c;
      r += histB[b]; c += histB[b] + npb;
    }
    rbase[NB] = r;
    start[N_NODES] = c;   // == E + N_NODES
  }
}

__global__ __launch_bounds__(256) void k_binA(const int* __restrict__ src,
    const int* __restrict__ dst, const float* __restrict__ ew, int E,
    const int* __restrict__ rbase, const int* __restrict__ hists,
    int* __restrict__ gcur, uint2* __restrict__ bins) {
  __shared__ int gb[NB], cur[NB];
  for (int i = threadIdx.x; i < NB; i += 256) {
    int hv = hists[blockIdx.x * NB + i];
    cur[i] = 0;
    gb[i] = hv ? (rbase[i] + atomicAdd(&gcur[i], hv)) : 0;
  }
  __syncthreads();
  int base = blockIdx.x * EPB;
  for (int i = threadIdx.x; i < EPB; i += 256) {
    int e = base + i;
    if (e < E) {
      int d = dst[e];
      int g = d >> 8;
      int p = gb[g] + atomicAdd(&cur[g], 1);
      bins[p] = make_uint2((uint32)src[e] | ((uint32)(d & 255) << 16),
                           __float_as_uint(ew[e]));
    }
  }
}

__global__ __launch_bounds__(256) void k_binB(const uint2* __restrict__ bins,
    const int* __restrict__ rbase, const int* __restrict__ cbase,
    int* __restrict__ start, float* __restrict__ dinv, uint32* __restrict__ csr) {
  __shared__ int h[256], cur[256], ofs[256], sc[256];
  __shared__ float deg[256];
  int tid = threadIdx.x;
  int b = blockIdx.x;
  int node0 = b << 8;
  int npb = min(NPB, N_NODES - node0);
  h[tid] = 0; deg[tid] = 1.0f;
  __syncthreads();
  int r0 = rbase[b], r1 = rbase[b + 1];
  for (int i = r0 + tid; i < r1; i += 256) {
    uint2 rec = bins[i];
    int dl = (rec.x >> 16) & 255;
    atomicAdd(&h[dl], 1);
    atomicAdd(&deg[dl], __uint_as_float(rec.y));
  }
  __syncthreads();
  int v = (tid < npb) ? 1 + h[tid] : 0;
  sc[tid] = v;
  __syncthreads();
  for (int off = 1; off < 256; off <<= 1) {
    int a = (tid >= off) ? sc[tid - off] : 0;
    __syncthreads();
    sc[tid] += a;
    __syncthreads();
  }
  int cb = cbase[b];
  if (tid < npb) {
    int segBase = cb + sc[tid] - v;
    int node = node0 + tid;
    start[node] = segBase;
    csr[segBase] = (0x3F80u << 16) | (uint32)node;   // self: w=1.0
    dinv[node] = rsqrtf(deg[tid]);
    ofs[tid] = segBase + 1;
    cur[tid] = 0;
  }
  __syncthreads();
  for (int i = r0 + tid; i < r1; i += 256) {
    uint2 rec = bins[i];
    int dl = (rec.x >> 16) & 255;
    int p = ofs[dl] + atomicAdd(&cur[dl], 1);
    csr[p] = ((uint32)bf16rn(__uint_as_float(rec.y)) << 16) | (rec.x & 0xffff);
  }
}

__global__ __launch_bounds__(256) void k_wnorm(uint32* __restrict__ csr,
    const int* __restrict__ start, const float* __restrict__ dinv) {
  int lane = threadIdx.x & 15;
  int node = blockIdx.x * 16 + (threadIdx.x >> 4);
  if (node >= N_NODES) return;
  float di = dinv[node];
  int e0 = start[node], e1 = start[node + 1];
  for (int e = e0 + lane; e < e1; e += 16) {
    uint32 c = csr[e];
    int s = c & 0xffff;
    float w = unbf(c >> 16) * dinv[s] * di;
    csr[e] = ((uint32)bf16rn(w) << 16) | (uint32)s;
  }
}

// ---------------- MFMA GEMM (+ fused BN+ReLU on input via precomputed ssb) ----------------

template <int BNT, typename XT>
__global__ __launch_bounds__(256) void k_mfma(const XT* __restrict__ X,
    const ushort* __restrict__ Wt, const float* __restrict__ ssb,
    ushort* __restrict__ out16, int Fout) {
  __shared__ ushort Xs[64][136];
  __shared__ ushort Bs[BNT * 16][136];
  int tid = threadIdx.x;
  int r0 = blockIdx.x * 64;

  // stage Bs[col][k]
  for (int idx = tid; idx < BNT * 16 * 16; idx += 256) {
    int col = idx >> 4;
    int kk = (idx & 15) * 8;
    uint4 v = make_uint4(0, 0, 0, 0);
    if (col < Fout)
      v = *reinterpret_cast<const uint4*>(&Wt[(size_t)col * 128 + kk]);
    *reinterpret_cast<uint4*>(&Bs[col][kk]) = v;
  }

  // stage Xs[row][k]
  if (sizeof(XT) == 4) {
    const float* Xf = reinterpret_cast<const float*>(X);
    for (int idx = tid; idx < 2048; idx += 256) {
      int row = idx >> 5;
      int kk = (idx & 31) * 4;
      int gr = r0 + row;
      float4 v = make_float4(0.f, 0.f, 0.f, 0.f);
      if (gr < N_NODES)
        v = *reinterpret_cast<const float4*>(&Xf[(size_t)gr * 128 + kk]);
      ushort4 o;
      o.x = bf16rn(v.x); o.y = bf16rn(v.y); o.z = bf16rn(v.z); o.w = bf16rn(v.w);
      *reinterpret_cast<ushort4*>(&Xs[row][kk]) = o;
    }
  } else {
    const ushort* X16 = reinterpret_cast<const ushort*>(X);
    for (int idx = tid; idx < 1024; idx += 256) {
      int row = idx >> 4;
      int kk = (idx & 15) * 8;
      int gr = r0 + row;
      uint4 v = make_uint4(0, 0, 0, 0);
      if (gr < N_NODES)
        v = *reinterpret_cast<const uint4*>(&X16[(size_t)gr * 128 + kk]);
      if (ssb) {
        float f[8] = { lo16(v.x), hi16(v.x), lo16(v.y), hi16(v.y),
                       lo16(v.z), hi16(v.z), lo16(v.w), hi16(v.w) };
        float4 sc0 = *reinterpret_cast<const float4*>(&ssb[kk]);
        float4 sc1 = *reinterpret_cast<const float4*>(&ssb[kk + 4]);
        float4 sh0 = *reinterpret_cast<const float4*>(&ssb[128 + kk]);
        float4 sh1 = *reinterpret_cast<const float4*>(&ssb[128 + kk + 4]);
        f[0] = fmaxf(0.f, f[0] * sc0.x + sh0.x);
        f[1] = fmaxf(0.f, f[1] * sc0.y + sh0.y);
        f[2] = fmaxf(0.f, f[2] * sc0.z + sh0.z);
        f[3] = fmaxf(0.f, f[3] * sc0.w + sh0.w);
        f[4] = fmaxf(0.f, f[4] * sc1.x + sh1.x);
        f[5] = fmaxf(0.f, f[5] * sc1.y + sh1.y);
        f[6] = fmaxf(0.f, f[6] * sc1.z + sh1.z);
        f[7] = fmaxf(0.f, f[7] * sc1.w + sh1.w);
        v.x = pack2(f[0], f[1]); v.y = pack2(f[2], f[3]);
        v.z = pack2(f[4], f[5]); v.w = pack2(f[6], f[7]);
      }
      *reinterpret_cast<uint4*>(&Xs[row][kk]) = v;
    }
  }
  __syncthreads();

  int lane = tid & 63, wav = tid >> 6;
  int lrow = lane & 15, lk = (lane >> 4) * 8;
  f32x4 acc[BNT];
  #pragma unroll
  for (int ct = 0; ct < BNT; ++ct) acc[ct] = (f32x4){0.f, 0.f, 0.f, 0.f};

  #pragma unroll
  for (int kc = 0; kc < 4; ++kc) {
    int k0 = kc * 32 + lk;
    bf16x8 a = *reinterpret_cast<const bf16x8*>(&Xs[wav * 16 + lrow][k0]);
    #pragma unroll
    for (int ct = 0; ct < BNT; ++ct) {
      bf16x8 b = *reinterpret_cast<const bf16x8*>(&Bs[ct * 16 + lrow][k0]);
      acc[ct] = __builtin_amdgcn_mfma_f32_16x16x32_bf16(a, b, acc[ct], 0, 0, 0);
    }
  }

  int orow = wav * 16 + (lane >> 4) * 4;
  #pragma unroll
  for (int ct = 0; ct < BNT; ++ct) {
    int gc = ct * 16 + lrow;
    if (gc >= Fout) continue;
    #pragma unroll
    for (int i = 0; i < 4; ++i) {
      int gr = r0 + orow + i;
      if (gr < N_NODES) out16[(size_t)gr * Fout + gc] = bf16rn(acc[ct][i]);
    }
  }
}

// ---------------- aggregation: 1 wave/node, 8 rows in flight ----------------

__global__ __launch_bounds__(256) void k_agg128c(const ushort* __restrict__ xw,
    const float* __restrict__ bias, const int* __restrict__ start,
    const uint32* __restrict__ csr, ushort* __restrict__ out16) {
  int lane = threadIdx.x & 63;
  int node = blockIdx.x * 4 + (threadIdx.x >> 6);
  if (node >= N_NODES) return;
  int sub = lane >> 4;
  int fl  = lane & 15;
  const uint4* rows = (const uint4*)xw;
  float acc[8] = {};
  int e0 = start[node], e1 = start[node + 1];
  int e = e0 + sub;
  for (; e + 4 < e1; e += 8) {
    uint32 c0 = csr[e], c1 = csr[e + 4];
    uint4 v0 = rows[(size_t)(c0 & 0xffff) * 16 + fl];
    uint4 v1 = rows[(size_t)(c1 & 0xffff) * 16 + fl];
    float w0 = unbf(c0 >> 16), w1 = unbf(c1 >> 16);
    acc[0] += w0 * lo16(v0.x) + w1 * lo16(v1.x);
    acc[1] += w0 * hi16(v0.x) + w1 * hi16(v1.x);
    acc[2] += w0 * lo16(v0.y) + w1 * lo16(v1.y);
    acc[3] += w0 * hi16(v0.y) + w1 * hi16(v1.y);
    acc[4] += w0 * lo16(v0.z) + w1 * lo16(v1.z);
    acc[5] += w0 * hi16(v0.z) + w1 * hi16(v1.z);
    acc[6] += w0 * lo16(v0.w) + w1 * lo16(v1.w);
    acc[7] += w0 * hi16(v0.w) + w1 * hi16(v1.w);
  }
  if (e < e1) {
    uint32 c = csr[e];
    float w = unbf(c >> 16);
    uint4 v = rows[(size_t)(c & 0xffff) * 16 + fl];
    acc[0] += w * lo16(v.x); acc[1] += w * hi16(v.x);
    acc[2] += w * lo16(v.y); acc[3] += w * hi16(v.y);
    acc[4] += w * lo16(v.z); acc[5] += w * hi16(v.z);
    acc[6] += w * lo16(v.w); acc[7] += w * hi16(v.w);
  }
  #pragma unroll
  for (int k = 0; k < 8; ++k) acc[k] += __shfl_xor(acc[k], 16);
  #pragma unroll
  for (int k = 0; k < 8; ++k) acc[k] += __shfl_xor(acc[k], 32);
  if (sub == 0) {
    float4 b0 = ((const float4*)bias)[fl * 2];
    float4 b1 = ((const float4*)bias)[fl * 2 + 1];
    acc[0] += b0.x; acc[1] += b0.y; acc[2] += b0.z; acc[3] += b0.w;
    acc[4] += b1.x; acc[5] += b1.y; acc[6] += b1.z; acc[7] += b1.w;
    uint4 o;
    o.x = pack2(acc[0], acc[1]);
    o.y = pack2(acc[2], acc[3]);
    o.z = pack2(acc[4], acc[5]);
    o.w = pack2(acc[6], acc[7]);
    ((uint4*)out16)[(size_t)node * 16 + fl] = o;
  }
}

// ---------------- agg (40 cols) + fused log_softmax ----------------

__global__ __launch_bounds__(256) void k_agg40lsm(const ushort* __restrict__ xw,
    const float* __restrict__ bias, const int* __restrict__ start,
    const uint32* __restrict__ csr, float* __restrict__ out) {
  int lane = threadIdx.x & 63;
  int node = blockIdx.x * 4 + (threadIdx.x >> 6);
  if (node >= N_NODES) return;
  int sub = lane >> 4;
  int fl  = lane & 15;
  bool active = fl < 10;
  int flc = active ? fl : 0;
  const uint2* rows = (const uint2*)xw;
  float acc[4] = {};
  int e0 = start[node], e1 = start[node + 1];
  for (int e = e0 + sub; e < e1; e += 4) {
    uint32 c = csr[e];
    float w = unbf(c >> 16);
    int s = c & 0xffff;
    uint2 v = rows[(size_t)s * 10 + flc];
    if (active) {
      acc[0] += w * lo16(v.x); acc[1] += w * hi16(v.x);
      acc[2] += w * lo16(v.y); acc[3] += w * hi16(v.y);
    }
  }
  #pragma unroll
  for (int k = 0; k < 4; ++k) acc[k] += __shfl_xor(acc[k], 16);
  #pragma unroll
  for (int k = 0; k < 4; ++k) acc[k] += __shfl_xor(acc[k], 32);
  if (sub == 0) {
    float m = -1e30f, es = 0.f;
    if (active) {
      float4 b = ((const float4*)bias)[fl];
      acc[0] += b.x; acc[1] += b.y; acc[2] += b.z; acc[3] += b.w;
      m = fmaxf(fmaxf(acc[0], acc[1]), fmaxf(acc[2], acc[3]));
    }
    #pragma unroll
    for (int off = 8; off >= 1; off >>= 1) m = fmaxf(m, __shfl_xor(m, off, 16));
    if (active)
      es = expf(acc[0] - m) + expf(acc[1] - m) + expf(acc[2] - m) + expf(acc[3] - m);
    #pragma unroll
    for (int off = 8; off >= 1; off >>= 1) es += __shfl_xor(es, off, 16);
    if (active) {
      float lse = m + logf(es);
      float4 o = make_float4(acc[0] - lse, acc[1] - lse, acc[2] - lse, acc[3] - lse);
      *reinterpret_cast<float4*>(&out[(size_t)node * 40 + fl * 4]) = o;
    }
  }
}

// ---------------- batch norm stats: stage 1 (no atomics, per-block partials) ----------------

__global__ __launch_bounds__(256) void k_bnstats1(const ushort* __restrict__ x,
    float* __restrict__ partials) {
  int fl = threadIdx.x & 15;     // feature group (8 features)
  int rg = threadIdx.x >> 4;     // 16 row-groups
  float s[8] = {}, q[8] = {};
  const uint4* xv = (const uint4*)x;
  for (int row = blockIdx.x * 16 + rg; row < N_NODES; row += BN_BLOCKS * 16) {
    uint4 v = xv[(size_t)row * 16 + fl];
    float f0 = lo16(v.x), f1 = hi16(v.x), f2 = lo16(v.y), f3 = hi16(v.y);
    float f4 = lo16(v.z), f5 = hi16(v.z), f6 = lo16(v.w), f7 = hi16(v.w);
    s[0] += f0; q[0] += f0 * f0; s[1] += f1; q[1] += f1 * f1;
    s[2] += f2; q[2] += f2 * f2; s[3] += f3; q[3] += f3 * f3;
    s[4] += f4; q[4] += f4 * f4; s[5] += f5; q[5] += f5 * f5;
    s[6] += f6; q[6] += f6 * f6; s[7] += f7; q[7] += f7 * f7;
  }
  __shared__ float ls[256][8];
  __shared__ float lq[256][8];
  #pragma unroll
  for (int j = 0; j < 8; ++j) { ls[threadIdx.x][j] = s[j]; lq[threadIdx.x][j] = q[j]; }
  __syncthreads();
  // tree-reduce over the 16 row-groups
  for (int step = 8; step >= 1; step >>= 1) {
    if (rg < step) {
      #pragma unroll
      for (int j = 0; j < 8; ++j) {
        ls[rg * 16 + fl][j] += ls[(rg + step) * 16 + fl][j];
        lq[rg * 16 + fl][j] += lq[(rg + step) * 16 + fl][j];
      }
    }
    __syncthreads();
  }
  if (rg == 0) {
    #pragma unroll
    for (int j = 0; j < 8; ++j) {
      partials[(size_t)blockIdx.x * 256 + fl * 8 + j] = ls[fl][j];
      partials[(size_t)blockIdx.x * 256 + 128 + fl * 8 + j] = lq[fl][j];
    }
  }
}

// ---------------- stage 2: reduce partials + compute BN scale/shift ----------------

__global__ __launch_bounds__(256) void k_bnred(const float* __restrict__ partials,
    const float* __restrict__ gamma, const float* __restrict__ beta,
    float* __restrict__ ssb) {
  int tid = threadIdx.x;   // 256
  float s = 0.f;
  for (int b = 0; b < BN_BLOCKS; ++b) s += partials[(size_t)b * 256 + tid];
  __shared__ float st[256];
  st[tid] = s;
  __syncthreads();
  if (tid < 128) {
    float inv_n = 1.0f / (float)N_NODES;
    float mu = st[tid] * inv_n;
    float var = st[128 + tid] * inv_n - mu * mu;
    if (var < 0.f) var = 0.f;
    float sc = gamma[tid] * rsqrtf(var + BN_EPS);
    ssb[tid] = sc;
    ssb[128 + tid] = beta[tid] - mu * sc;
  }
}

// ---------------- launch ----------------

extern "C" void kernel_launch(void* const* d_in, const int* in_sizes, int n_in,
                              void* d_out, int out_size, void* d_ws, size_t ws_size,
                              hipStream_t stream) {
  const float* x   = (const float*)d_in[0];
  const int*   ei  = (const int*)d_in[1];
  const float* ew  = (const float*)d_in[2];
  const float* W1  = (const float*)d_in[3];
  const float* b1  = (const float*)d_in[4];
  const float* g1  = (const float*)d_in[5];
  const float* be1 = (const float*)d_in[6];
  const float* W2  = (const float*)d_in[7];
  const float* b2  = (const float*)d_in[8];
  const float* g2  = (const float*)d_in[9];
  const float* be2 = (const float*)d_in[10];
  const float* W3  = (const float*)d_in[11];
  const float* b3  = (const float*)d_in[12];
  float* out = (float*)d_out;
  int E = in_sizes[2];
  const int* src = ei;
  const int* dst = ei + E;
  int nblkA = (E + EPB - 1) / EPB;

  char* p = (char*)d_ws;
  auto alloc = [&](size_t bytes) {
    char* r = p; p += (bytes + 255) & ~(size_t)255; return r;
  };
  // zero-initialized region (single memset): histB, gcur
  int*    histB  = (int*)   alloc((size_t)(NB + 1) * 4);
  int*    gcur   = (int*)   alloc((size_t)NB * 4);
  size_t zspan = (size_t)((char*)gcur + (size_t)NB * 4 - (char*)histB);
  int*    rbase  = (int*)   alloc((size_t)(NB + 1) * 4);
  int*    cbase  = (int*)   alloc((size_t)NB * 4);
  int*    hists  = (int*)   alloc((size_t)nblkA * NB * 4);
  int*    startA = (int*)   alloc((size_t)(N_NODES + 1) * 4);
  float*  dinv   = (float*) alloc((size_t)N_NODES * 4);
  uint2*  bins   = (uint2*) alloc((size_t)E * 8);
  uint32* csr    = (uint32*)alloc((size_t)(E + N_NODES) * 4);
  float*  parts  = (float*) alloc((size_t)BN_BLOCKS * 256 * 4);
  float*  ssb1   = (float*) alloc(256 * 4);
  float*  ssb2   = (float*) alloc(256 * 4);
  ushort* Wt1    = (ushort*)alloc((size_t)128 * 128 * 2);
  ushort* Wt2    = (ushort*)alloc((size_t)128 * 128 * 2);
  ushort* Wt3    = (ushort*)alloc((size_t)40 * 128 * 2);
  ushort* xw16   = (ushort*)alloc((size_t)N_NODES * 128 * 2);
  ushort* buf16  = (ushort*)alloc((size_t)N_NODES * 128 * 2);

  hipMemsetAsync(histB, 0, zspan, stream);
  k_cvtW_all<<<149, 256, 0, stream>>>(W1, W2, W3, Wt1, Wt2, Wt3);
  k_ehist<<<nblkA, 256, 0, stream>>>(dst, E, histB, hists);
  k_prefix<<<1, 64, 0, stream>>>(histB, E, rbase, cbase, startA);
  k_binA<<<nblkA, 256, 0, stream>>>(src, dst, ew, E, rbase, hists, gcur, bins);
  k_binB<<<NB, 256, 0, stream>>>(bins, rbase, cbase, startA, dinv, csr);
  k_wnorm<<<(N_NODES + 15) / 16, 256, 0, stream>>>(csr, startA, dinv);

  int gemmGrid = (N_NODES + 63) / 64;   // 782
  int aggGrid = (N_NODES + 3) / 4;

  // layer 1
  k_mfma<8, float><<<gemmGrid, 256, 0, stream>>>(x, Wt1, nullptr, xw16, 128);
  k_agg128c<<<aggGrid, 256, 0, stream>>>(xw16, b1, startA, csr, buf16);
  k_bnstats1<<<BN_BLOCKS, 256, 0, stream>>>(buf16, parts);
  k_bnred<<<1, 256, 0, stream>>>(parts, g1, be1, ssb1);

  // layer 2 (BN1+ReLU fused into GEMM staging)
  k_mfma<8, ushort><<<gemmGrid, 256, 0, stream>>>(buf16, Wt2, ssb1, xw16, 128);
  k_agg128c<<<aggGrid, 256, 0, stream>>>(xw16, b2, startA, csr, buf16);
  k_bnstats1<<<BN_BLOCKS, 256, 0, stream>>>(buf16, parts);
  k_bnred<<<1, 256, 0, stream>>>(parts, g2, be2, ssb2);

  // layer 3 (BN2+ReLU fused into GEMM staging; agg + log_softmax fused)
  k_mfma<3, ushort><<<gemmGrid, 256, 0, stream>>>(buf16, Wt3, ssb2, xw16, 40);
  k_agg40lsm<<<aggGrid, 256, 0, stream>>>(xw16, b3, startA, csr, out);
}